// Round 11
// baseline (102.014 us; speedup 1.0000x reference)
//
#include <hip/hip_runtime.h>
#include <math.h>

#define B_  32
#define C_  256
#define H_  64
#define W_  64
#define HW  (H_*W_)          // 4096
#define HW4 (HW/4)           // 1024
#define RPB 4                // channel rows per block (grid 2048 = 8 blocks/CU)

typedef float f32x4 __attribute__((ext_vector_type(4)));

__device__ __forceinline__ float clamp01(float v) {
    return fminf(fmaxf(v, 0.0f), 1.0f);
}

// XCD-contiguity swizzle: grid 2048, 8 XCDs round-robin on blockIdx.
// job = (blk&7)*256 + (blk>>3)  => XCD k owns jobs [k*256, (k+1)*256) =
// 4 whole batches (64 jobs/batch): rm reuse stays in one L2, feat/out slab
// is 16 MB contiguous per XCD.
__device__ __forceinline__ int swz2048(int blk) {
    return (blk & 7) * 256 + (blk >> 3);
}

struct BoxParams {
    float bx1, by1, bx2, by2, mx1, my1, mx2, my2;
};

__device__ __forceinline__ BoxParams box_math(const float* __restrict__ xywh, int b) {
    const float xc = xywh[b * 4 + 0];
    const float yc = xywh[b * 4 + 1];
    const float bw = xywh[b * 4 + 2];
    const float bh = xywh[b * 4 + 3];

    float x1 = clamp01(xc - bw * 0.5f);
    float y1 = clamp01(yc - bh * 0.5f);
    float x2 = clamp01(xc + bw * 0.5f);
    float y2 = clamp01(yc + bh * 0.5f);
    float xl = fminf(x1, x2), xh = fmaxf(x1, x2);
    float yl = fminf(y1, y2), yh = fmaxf(y1, y2);
    float w_ = fmaxf(xh - xl, 1e-6f);
    float h_ = fmaxf(yh - yl, 1e-6f);
    float cx = (xh + xl) * 0.5f, cy = (yh + yl) * 0.5f;
    BoxParams p;
    p.bx1 = clamp01(cx - w_ * 0.5f);
    p.by1 = clamp01(cy - h_ * 0.5f);
    p.bx2 = clamp01(cx + w_ * 0.5f);
    p.by2 = clamp01(cy + h_ * 0.5f);
    float ww = fmaxf(p.bx2 - p.bx1, 1e-4f);
    float hh = fmaxf(p.by2 - p.by1, 1e-4f);
    float diag = sqrtf(ww * ww + hh * hh);
    float margin = fminf(fmaxf(diag * 0.2f, 0.02f), 0.2f);
    p.mx1 = clamp01(p.bx1 - margin);
    p.my1 = clamp01(p.by1 - margin);
    p.mx2 = clamp01(p.bx2 + margin);
    p.my2 = clamp01(p.by2 + margin);
    return p;
}

__device__ __forceinline__ void build_tables(
    int t, const BoxParams& p, float b2v,
    const float* sw1, const float* sb1, const float* sw2,
    int* xpat, int* ypat, float* tbl)
{
    if (t < 64) {
        const int x = t;
        int pp = 0;
        #pragma unroll
        for (int k = 0; k < 3; ++k) {
            const int xx = x + k - 1;
            float gx = (float)((double)xx / 63.0);
            bool in = (xx >= 0) && (xx < W_) && (gx >= p.mx1) && (gx <= p.mx2);
            pp |= (in ? 1 : 0) << k;
        }
        xpat[x] = pp;
    } else if (t < 128) {
        const int y = t - 64;
        int pp = 0;
        #pragma unroll
        for (int k = 0; k < 3; ++k) {
            const int yy = y + k - 1;
            float gy = (float)((double)yy / 63.0);
            bool in = (yy >= 0) && (yy < H_) && (gy >= p.my1) && (gy <= p.my2);
            pp |= (in ? 1 : 0) << k;
        }
        ypat[y] = pp;
    } else if (t < 192) {
        const int e = t - 128;           // e = yp*8 + xp
        const int xp = e & 7, yp = e >> 3;
        float mv[9];
        #pragma unroll
        for (int ky = 0; ky < 3; ++ky)
            #pragma unroll
            for (int kx = 0; kx < 3; ++kx)
                mv[ky * 3 + kx] = (((yp >> ky) & 1) && ((xp >> kx) & 1)) ? 1.0f : 0.0f;
        float z = b2v;
        #pragma unroll
        for (int oc = 0; oc < 16; ++oc) {
            float hsum = sb1[oc];
            #pragma unroll
            for (int k = 0; k < 9; ++k) hsum = fmaf(mv[k], sw1[oc * 9 + k], hsum);
            z = fmaf(fmaxf(hsum, 0.0f), sw2[oc], z);
        }
        tbl[e] = 1.0f / (1.0f + expf(-z));
    }
}

// ---------------------------------------------------------------------------
// K0: mask kernel. 4 blocks per batch -> rm (global) + partial areas.
// ---------------------------------------------------------------------------
__global__ __launch_bounds__(256) void kern_mask(
    const float* __restrict__ xywh,
    const float* __restrict__ conv1_w, const float* __restrict__ conv1_b,
    const float* __restrict__ conv2_w, const float* __restrict__ conv2_b,
    float* __restrict__ out_boxes, float* __restrict__ out_rm,
    float* __restrict__ ws_part)
{
    const int b = blockIdx.x >> 2;
    const int q = blockIdx.x & 3;
    const int t = threadIdx.x;

    __shared__ float sw1[16 * 9];
    __shared__ float sb1[16];
    __shared__ float sw2[16];
    __shared__ float tbl[64];
    __shared__ int   xpat[64];
    __shared__ int   ypat[64];
    __shared__ float sred[4];

    if (t < 144)                 sw1[t]       = conv1_w[t];
    else if (t < 160)            sb1[t - 144] = conv1_b[t - 144];
    else if (t < 176)            sw2[t - 160] = conv2_w[t - 160];
    const float b2v = conv2_b[0];

    const BoxParams bp = box_math(xywh, b);
    if (t == 0 && q == 0) {
        out_boxes[b * 4 + 0] = bp.bx1;
        out_boxes[b * 4 + 1] = bp.by1;
        out_boxes[b * 4 + 2] = bp.bx2;
        out_boxes[b * 4 + 3] = bp.by2;
    }
    __syncthreads();

    build_tables(t, bp, b2v, sw1, sb1, sw2, xpat, ypat, tbl);
    __syncthreads();

    float asum = 0.0f;
    const int p0 = q * 1024;
    for (int pi = t; pi < 1024; pi += 256) {
        const int p = p0 + pi;
        const int y = p >> 6;
        const int x = p & 63;
        float rm = tbl[ypat[y] * 8 + xpat[x]];
        out_rm[b * HW + p] = rm;
        asum += rm;
    }
    #pragma unroll
    for (int off = 32; off > 0; off >>= 1) asum += __shfl_down(asum, off, 64);
    int lane = t & 63, wid = t >> 6;
    if (lane == 0) sred[wid] = asum;
    __syncthreads();
    if (t == 0) ws_part[b * 4 + q] = sred[0] + sred[1] + sred[2] + sred[3];
}

// ---------------------------------------------------------------------------
// K1: pf. XCD-swizzled; rm from global (L2-hot). Burst: per unrolled step,
// 10 loads (2 rm + 8 feat) issued back-to-back, then FMAs. ~60 VGPR.
// ---------------------------------------------------------------------------
__global__ __launch_bounds__(256) void kern_pf(
    const float* __restrict__ feat, const float* __restrict__ rm,
    const float* __restrict__ ws_part, float* __restrict__ out_pf)
{
    const int job = swz2048(blockIdx.x);  // b*64 + g
    const int b = job >> 6;
    const int c0 = (job & 63) * RPB;
    const int t = threadIdx.x;
    __shared__ f32x4 sredv[4];

    const f32x4* fr = (const f32x4*)(feat + ((size_t)b * C_ + c0) * HW);
    const f32x4* r4 = (const f32x4*)(rm + (size_t)b * HW);

    float s0 = 0.f, s1 = 0.f, s2 = 0.f, s3 = 0.f;
    #pragma unroll
    for (int k = 0; k < 2; ++k) {
        const int i0 = t + k * 512;
        const int i1 = i0 + 256;
        // burst: 10 independent loads
        f32x4 ra = r4[i0];
        f32x4 rb = r4[i1];
        f32x4 a0 = fr[i0];
        f32x4 a1 = fr[i0 + HW4];
        f32x4 a2 = fr[i0 + 2 * HW4];
        f32x4 a3 = fr[i0 + 3 * HW4];
        f32x4 b0 = fr[i1];
        f32x4 b1 = fr[i1 + HW4];
        f32x4 b2 = fr[i1 + 2 * HW4];
        f32x4 b3 = fr[i1 + 3 * HW4];
        s0 = fmaf(a0.x, ra.x, fmaf(a0.y, ra.y, fmaf(a0.z, ra.z, fmaf(a0.w, ra.w, s0))));
        s1 = fmaf(a1.x, ra.x, fmaf(a1.y, ra.y, fmaf(a1.z, ra.z, fmaf(a1.w, ra.w, s1))));
        s2 = fmaf(a2.x, ra.x, fmaf(a2.y, ra.y, fmaf(a2.z, ra.z, fmaf(a2.w, ra.w, s2))));
        s3 = fmaf(a3.x, ra.x, fmaf(a3.y, ra.y, fmaf(a3.z, ra.z, fmaf(a3.w, ra.w, s3))));
        s0 = fmaf(b0.x, rb.x, fmaf(b0.y, rb.y, fmaf(b0.z, rb.z, fmaf(b0.w, rb.w, s0))));
        s1 = fmaf(b1.x, rb.x, fmaf(b1.y, rb.y, fmaf(b1.z, rb.z, fmaf(b1.w, rb.w, s1))));
        s2 = fmaf(b2.x, rb.x, fmaf(b2.y, rb.y, fmaf(b2.z, rb.z, fmaf(b2.w, rb.w, s2))));
        s3 = fmaf(b3.x, rb.x, fmaf(b3.y, rb.y, fmaf(b3.z, rb.z, fmaf(b3.w, rb.w, s3))));
    }

    #pragma unroll
    for (int off = 32; off > 0; off >>= 1) {
        s0 += __shfl_down(s0, off, 64);
        s1 += __shfl_down(s1, off, 64);
        s2 += __shfl_down(s2, off, 64);
        s3 += __shfl_down(s3, off, 64);
    }
    const int lane = t & 63, wid = t >> 6;
    if (lane == 0) { f32x4 v; v.x = s0; v.y = s1; v.z = s2; v.w = s3; sredv[wid] = v; }
    __syncthreads();
    if (t == 0) {
        float area = fmaxf(ws_part[b * 4 + 0] + ws_part[b * 4 + 1] +
                           ws_part[b * 4 + 2] + ws_part[b * 4 + 3], 1.0f);
        float inv = 1.0f / area;
        f32x4 t0 = sredv[0], t1 = sredv[1], t2 = sredv[2], t3 = sredv[3];
        out_pf[b * C_ + c0 + 0] = (t0.x + t1.x + t2.x + t3.x) * inv;
        out_pf[b * C_ + c0 + 1] = (t0.y + t1.y + t2.y + t3.y) * inv;
        out_pf[b * C_ + c0 + 2] = (t0.z + t1.z + t2.z + t3.z) * inv;
        out_pf[b * C_ + c0 + 3] = (t0.w + t1.w + t2.w + t3.w) * inv;
    }
}

// ---------------------------------------------------------------------------
// K2: fused 2-layer MLP (unchanged).
// ---------------------------------------------------------------------------
__global__ __launch_bounds__(256) void kern_mlp(
    const float* __restrict__ pf, const float* __restrict__ lang,
    const float* __restrict__ cg_w1, const float* __restrict__ cg_b1,
    const float* __restrict__ cg_w2, const float* __restrict__ cg_b2,
    const float* __restrict__ lf_w1, const float* __restrict__ lf_b1,
    const float* __restrict__ lf_w2, const float* __restrict__ lf_b2,
    float* __restrict__ ws_cg, float* __restrict__ out_gl)
{
    const int b = blockIdx.x >> 1;
    const int which = blockIdx.x & 1;
    const int t = threadIdx.x;
    __shared__ float fus[512];
    __shared__ float hid[256];

    fus[t]       = pf[b * 256 + t];
    fus[256 + t] = lang[b * 256 + t];

    const float* w1 = which ? lf_w1 : cg_w1;
    const float* b1 = which ? lf_b1 : cg_b1;
    const float* w2 = which ? lf_w2 : cg_w2;
    const float* b2 = which ? lf_b2 : cg_b2;
    __syncthreads();

    const f32x4* wv = (const f32x4*)(w1 + (size_t)t * 512);
    const f32x4* fv = (const f32x4*)fus;
    float s = 0.0f;
    #pragma unroll 4
    for (int k = 0; k < 128; ++k) {
        f32x4 f = fv[k], w = wv[k];
        s = fmaf(f.x, w.x, fmaf(f.y, w.y, fmaf(f.z, w.z, fmaf(f.w, w.w, s))));
    }
    hid[t] = fmaxf(s + b1[t], 0.0f);
    __syncthreads();

    const f32x4* w2v = (const f32x4*)(w2 + (size_t)t * 256);
    const f32x4* hv = (const f32x4*)hid;
    float s2 = 0.0f;
    #pragma unroll 4
    for (int k = 0; k < 64; ++k) {
        f32x4 h = hv[k], w = w2v[k];
        s2 = fmaf(h.x, w.x, fmaf(h.y, w.y, fmaf(h.z, w.z, fmaf(h.w, w.w, s2))));
    }
    s2 += b2[t];
    if (which == 0) {
        ws_cg[b * 256 + t] = 1.0f + 0.5f / (1.0f + expf(-s2));   // pre-biased gate
    } else {
        out_gl[b * 256 + t] = fus[256 + t] + 0.4f * tanhf(s2);
    }
}

// ---------------------------------------------------------------------------
// K3: guided. XCD-swizzled; burst 10 loads -> compute -> 8 nt stores.
// ---------------------------------------------------------------------------
__global__ __launch_bounds__(256) void kern_guided(
    const float* __restrict__ feat, const float* __restrict__ rm,
    const float* __restrict__ ws_cg, float* __restrict__ out_gf)
{
    const int job = swz2048(blockIdx.x);  // b*64 + g
    const int b = job >> 6;
    const int c0 = (job & 63) * RPB;
    const int t = threadIdx.x;
    const float g0 = ws_cg[b * C_ + c0 + 0];
    const float g1 = ws_cg[b * C_ + c0 + 1];
    const float g2 = ws_cg[b * C_ + c0 + 2];
    const float g3 = ws_cg[b * C_ + c0 + 3];

    const size_t row0 = ((size_t)b * C_ + c0) * HW;
    const f32x4* fr = (const f32x4*)(feat + row0);
    f32x4* orow = (f32x4*)(out_gf + row0);
    const f32x4* r4 = (const f32x4*)(rm + (size_t)b * HW);

    #pragma unroll
    for (int k = 0; k < 2; ++k) {
        const int i0 = t + k * 512;
        const int i1 = i0 + 256;
        // burst: 10 independent loads
        f32x4 ra = r4[i0];
        f32x4 rb = r4[i1];
        f32x4 a0 = fr[i0];
        f32x4 a1 = fr[i0 + HW4];
        f32x4 a2 = fr[i0 + 2 * HW4];
        f32x4 a3 = fr[i0 + 3 * HW4];
        f32x4 b0 = fr[i1];
        f32x4 b1 = fr[i1 + HW4];
        f32x4 b2 = fr[i1 + 2 * HW4];
        f32x4 b3 = fr[i1 + 3 * HW4];

        f32x4 ma, mb;
        ma.x = 1.0f + 0.6f * ra.x; ma.y = 1.0f + 0.6f * ra.y;
        ma.z = 1.0f + 0.6f * ra.z; ma.w = 1.0f + 0.6f * ra.w;
        mb.x = 1.0f + 0.6f * rb.x; mb.y = 1.0f + 0.6f * rb.y;
        mb.z = 1.0f + 0.6f * rb.z; mb.w = 1.0f + 0.6f * rb.w;

        f32x4 o;
        o.x = a0.x * ma.x * g0; o.y = a0.y * ma.y * g0;
        o.z = a0.z * ma.z * g0; o.w = a0.w * ma.w * g0;
        __builtin_nontemporal_store(o, &orow[i0]);
        o.x = a1.x * ma.x * g1; o.y = a1.y * ma.y * g1;
        o.z = a1.z * ma.z * g1; o.w = a1.w * ma.w * g1;
        __builtin_nontemporal_store(o, &orow[i0 + HW4]);
        o.x = a2.x * ma.x * g2; o.y = a2.y * ma.y * g2;
        o.z = a2.z * ma.z * g2; o.w = a2.w * ma.w * g2;
        __builtin_nontemporal_store(o, &orow[i0 + 2 * HW4]);
        o.x = a3.x * ma.x * g3; o.y = a3.y * ma.y * g3;
        o.z = a3.z * ma.z * g3; o.w = a3.w * ma.w * g3;
        __builtin_nontemporal_store(o, &orow[i0 + 3 * HW4]);
        o.x = b0.x * mb.x * g0; o.y = b0.y * mb.y * g0;
        o.z = b0.z * mb.z * g0; o.w = b0.w * mb.w * g0;
        __builtin_nontemporal_store(o, &orow[i1]);
        o.x = b1.x * mb.x * g1; o.y = b1.y * mb.y * g1;
        o.z = b1.z * mb.z * g1; o.w = b1.w * mb.w * g1;
        __builtin_nontemporal_store(o, &orow[i1 + HW4]);
        o.x = b2.x * mb.x * g2; o.y = b2.y * mb.y * g2;
        o.z = b2.z * mb.z * g2; o.w = b2.w * mb.w * g2;
        __builtin_nontemporal_store(o, &orow[i1 + 2 * HW4]);
        o.x = b3.x * mb.x * g3; o.y = b3.y * mb.y * g3;
        o.z = b3.z * mb.z * g3; o.w = b3.w * mb.w * g3;
        __builtin_nontemporal_store(o, &orow[i1 + 3 * HW4]);
    }
}

extern "C" void kernel_launch(void* const* d_in, const int* in_sizes, int n_in,
                              void* d_out, int out_size, void* d_ws, size_t ws_size,
                              hipStream_t stream) {
    const float* feat     = (const float*)d_in[0];
    const float* lang     = (const float*)d_in[1];
    const float* xywh     = (const float*)d_in[2];
    const float* conv1_w  = (const float*)d_in[3];
    const float* conv1_b  = (const float*)d_in[4];
    const float* conv2_w  = (const float*)d_in[5];
    const float* conv2_b  = (const float*)d_in[6];
    const float* cg_w1    = (const float*)d_in[7];
    const float* cg_b1    = (const float*)d_in[8];
    const float* cg_w2    = (const float*)d_in[9];
    const float* cg_b2    = (const float*)d_in[10];
    const float* lf_w1    = (const float*)d_in[11];
    const float* lf_b1    = (const float*)d_in[12];
    const float* lf_w2    = (const float*)d_in[13];
    const float* lf_b2    = (const float*)d_in[14];

    float* out = (float*)d_out;
    const size_t N_GF = (size_t)B_ * C_ * HW;    // 33554432
    float* out_gf    = out;
    float* out_gl    = out_gf + N_GF;            // 8192
    float* out_boxes = out_gl + (size_t)B_ * C_; // 128
    float* out_rm    = out_boxes + B_ * 4;       // 131072
    float* out_pf    = out_rm + (size_t)B_ * HW; // 8192

    float* wsf     = (float*)d_ws;
    float* ws_part = wsf;                  // 128 partial areas
    float* ws_cg   = wsf + 128;            // 8192 pre-biased gates

    (void)ws_size; (void)in_sizes; (void)n_in; (void)out_size;

    kern_mask<<<B_ * 4, 256, 0, stream>>>(xywh, conv1_w, conv1_b, conv2_w, conv2_b,
                                          out_boxes, out_rm, ws_part);
    kern_pf<<<B_ * C_ / RPB, 256, 0, stream>>>(feat, out_rm, ws_part, out_pf);
    kern_mlp<<<B_ * 2, 256, 0, stream>>>(out_pf, lang,
                                         cg_w1, cg_b1, cg_w2, cg_b2,
                                         lf_w1, lf_b1, lf_w2, lf_b2,
                                         ws_cg, out_gl);
    kern_guided<<<B_ * C_ / RPB, 256, 0, stream>>>(feat, out_rm, ws_cg, out_gf);
}

// Round 12
// 97.028 us; speedup vs baseline: 1.0514x; 1.0514x over previous
//
#include <hip/hip_runtime.h>
#include <math.h>

#define B_  32
#define C_  256
#define H_  64
#define W_  64
#define HW  (H_*W_)          // 4096
#define HW4 (HW/4)           // 1024
#define RPB 4                // channel rows per block (grid 2048 = 8 blocks/CU)

typedef float f32x4 __attribute__((ext_vector_type(4)));

__device__ __forceinline__ float clamp01(float v) {
    return fminf(fmaxf(v, 0.0f), 1.0f);
}

struct BoxParams {
    float bx1, by1, bx2, by2, mx1, my1, mx2, my2;
};

__device__ __forceinline__ BoxParams box_math(const float* __restrict__ xywh, int b) {
    const float xc = xywh[b * 4 + 0];
    const float yc = xywh[b * 4 + 1];
    const float bw = xywh[b * 4 + 2];
    const float bh = xywh[b * 4 + 3];

    float x1 = clamp01(xc - bw * 0.5f);
    float y1 = clamp01(yc - bh * 0.5f);
    float x2 = clamp01(xc + bw * 0.5f);
    float y2 = clamp01(yc + bh * 0.5f);
    float xl = fminf(x1, x2), xh = fmaxf(x1, x2);
    float yl = fminf(y1, y2), yh = fmaxf(y1, y2);
    float w_ = fmaxf(xh - xl, 1e-6f);
    float h_ = fmaxf(yh - yl, 1e-6f);
    float cx = (xh + xl) * 0.5f, cy = (yh + yl) * 0.5f;
    BoxParams p;
    p.bx1 = clamp01(cx - w_ * 0.5f);
    p.by1 = clamp01(cy - h_ * 0.5f);
    p.bx2 = clamp01(cx + w_ * 0.5f);
    p.by2 = clamp01(cy + h_ * 0.5f);
    float ww = fmaxf(p.bx2 - p.bx1, 1e-4f);
    float hh = fmaxf(p.by2 - p.by1, 1e-4f);
    float diag = sqrtf(ww * ww + hh * hh);
    float margin = fminf(fmaxf(diag * 0.2f, 0.02f), 0.2f);
    p.mx1 = clamp01(p.bx1 - margin);
    p.my1 = clamp01(p.by1 - margin);
    p.mx2 = clamp01(p.bx2 + margin);
    p.my2 = clamp01(p.by2 + margin);
    return p;
}

__device__ __forceinline__ void build_tables(
    int t, const BoxParams& p, float b2v,
    const float* sw1, const float* sb1, const float* sw2,
    int* xpat, int* ypat, float* tbl)
{
    if (t < 64) {
        const int x = t;
        int pp = 0;
        #pragma unroll
        for (int k = 0; k < 3; ++k) {
            const int xx = x + k - 1;
            float gx = (float)((double)xx / 63.0);
            bool in = (xx >= 0) && (xx < W_) && (gx >= p.mx1) && (gx <= p.mx2);
            pp |= (in ? 1 : 0) << k;
        }
        xpat[x] = pp;
    } else if (t < 128) {
        const int y = t - 64;
        int pp = 0;
        #pragma unroll
        for (int k = 0; k < 3; ++k) {
            const int yy = y + k - 1;
            float gy = (float)((double)yy / 63.0);
            bool in = (yy >= 0) && (yy < H_) && (gy >= p.my1) && (gy <= p.my2);
            pp |= (in ? 1 : 0) << k;
        }
        ypat[y] = pp;
    } else if (t < 192) {
        const int e = t - 128;           // e = yp*8 + xp
        const int xp = e & 7, yp = e >> 3;
        float mv[9];
        #pragma unroll
        for (int ky = 0; ky < 3; ++ky)
            #pragma unroll
            for (int kx = 0; kx < 3; ++kx)
                mv[ky * 3 + kx] = (((yp >> ky) & 1) && ((xp >> kx) & 1)) ? 1.0f : 0.0f;
        float z = b2v;
        #pragma unroll
        for (int oc = 0; oc < 16; ++oc) {
            float hsum = sb1[oc];
            #pragma unroll
            for (int k = 0; k < 9; ++k) hsum = fmaf(mv[k], sw1[oc * 9 + k], hsum);
            z = fmaf(fmaxf(hsum, 0.0f), sw2[oc], z);
        }
        tbl[e] = 1.0f / (1.0f + expf(-z));
    }
}

// fills rm row (f32x4 layout) in LDS; returns this thread's partial area sum
__device__ __forceinline__ float fill_rm(
    int t, const int* xpat, const int* ypat, const float* tbl, float* rm_lds)
{
    float asum = 0.0f;
    for (int p = t; p < HW; p += 256) {
        const int y = p >> 6;
        const int x = p & 63;
        float rm = tbl[ypat[y] * 8 + xpat[x]];
        rm_lds[p] = rm;
        asum += rm;
    }
    return asum;
}

// ---------------------------------------------------------------------------
// K1: fused mask+pf. Header: tables -> rm in LDS + area. Hot loop: single
// contiguous 64 KB sweep per block, static row indexing (r = k>>2), rm from
// LDS only (no second global stream).
// ---------------------------------------------------------------------------
__global__ __launch_bounds__(256) void kern_pf(
    const float* __restrict__ feat, const float* __restrict__ xywh,
    const float* __restrict__ conv1_w, const float* __restrict__ conv1_b,
    const float* __restrict__ conv2_w, const float* __restrict__ conv2_b,
    float* __restrict__ out_boxes, float* __restrict__ out_rm,
    float* __restrict__ out_pf)
{
    const int blk = blockIdx.x;          // b*64 + g
    const int b = blk >> 6;
    const int g = blk & 63;
    const int c0 = g * RPB;
    const int t = threadIdx.x;

    __shared__ float sw1[16 * 9];
    __shared__ float sb1[16];
    __shared__ float sw2[16];
    __shared__ float tbl[64];
    __shared__ int   xpat[64];
    __shared__ int   ypat[64];
    __shared__ f32x4 rm4_lds[HW4];
    __shared__ float sreda[4];
    __shared__ f32x4 sredv[4];

    float* rm_lds = (float*)rm4_lds;

    if (t < 144)                 sw1[t]       = conv1_w[t];
    else if (t < 160)            sb1[t - 144] = conv1_b[t - 144];
    else if (t < 176)            sw2[t - 160] = conv2_w[t - 160];
    const float b2v = conv2_b[0];

    const BoxParams bp = box_math(xywh, b);
    if (t == 0 && g == 0) {
        out_boxes[b * 4 + 0] = bp.bx1;
        out_boxes[b * 4 + 1] = bp.by1;
        out_boxes[b * 4 + 2] = bp.bx2;
        out_boxes[b * 4 + 3] = bp.by2;
    }
    __syncthreads();

    build_tables(t, bp, b2v, sw1, sb1, sw2, xpat, ypat, tbl);
    __syncthreads();

    float asum = fill_rm(t, xpat, ypat, tbl, rm_lds);
    #pragma unroll
    for (int off = 32; off > 0; off >>= 1) asum += __shfl_down(asum, off, 64);
    const int lane = t & 63, wid = t >> 6;
    if (lane == 0) sreda[wid] = asum;
    __syncthreads();
    const float inv = 1.0f / fmaxf(sreda[0] + sreda[1] + sreda[2] + sreda[3], 1.0f);

    if (g == 0) {
        f32x4* orm = (f32x4*)(out_rm + (size_t)b * HW);
        for (int i = t; i < HW4; i += 256) orm[i] = rm4_lds[i];
    }

    // hot loop: one contiguous 64 KB sweep (4096 f32x4), row r = k>>2 static
    const f32x4* fs = (const f32x4*)(feat + ((size_t)b * C_ + c0) * HW);
    float s0 = 0.f, s1 = 0.f, s2 = 0.f, s3 = 0.f;
    #pragma unroll
    for (int r = 0; r < 4; ++r) {
        // 4-load burst within row r (contiguous with previous row's end)
        f32x4 f0 = fs[t + (r * 4 + 0) * 256];
        f32x4 f1 = fs[t + (r * 4 + 1) * 256];
        f32x4 f2 = fs[t + (r * 4 + 2) * 256];
        f32x4 f3 = fs[t + (r * 4 + 3) * 256];
        f32x4 r0 = rm4_lds[t];
        f32x4 r1 = rm4_lds[t + 256];
        f32x4 r2 = rm4_lds[t + 512];
        f32x4 r3 = rm4_lds[t + 768];
        float acc = 0.0f;
        acc = fmaf(f0.x, r0.x, fmaf(f0.y, r0.y, fmaf(f0.z, r0.z, fmaf(f0.w, r0.w, acc))));
        acc = fmaf(f1.x, r1.x, fmaf(f1.y, r1.y, fmaf(f1.z, r1.z, fmaf(f1.w, r1.w, acc))));
        acc = fmaf(f2.x, r2.x, fmaf(f2.y, r2.y, fmaf(f2.z, r2.z, fmaf(f2.w, r2.w, acc))));
        acc = fmaf(f3.x, r3.x, fmaf(f3.y, r3.y, fmaf(f3.z, r3.z, fmaf(f3.w, r3.w, acc))));
        if (r == 0) s0 = acc; else if (r == 1) s1 = acc;
        else if (r == 2) s2 = acc; else s3 = acc;
    }

    #pragma unroll
    for (int off = 32; off > 0; off >>= 1) {
        s0 += __shfl_down(s0, off, 64);
        s1 += __shfl_down(s1, off, 64);
        s2 += __shfl_down(s2, off, 64);
        s3 += __shfl_down(s3, off, 64);
    }
    if (lane == 0) { f32x4 v; v.x = s0; v.y = s1; v.z = s2; v.w = s3; sredv[wid] = v; }
    __syncthreads();
    if (t == 0) {
        f32x4 t0 = sredv[0], t1 = sredv[1], t2 = sredv[2], t3 = sredv[3];
        out_pf[b * C_ + c0 + 0] = (t0.x + t1.x + t2.x + t3.x) * inv;
        out_pf[b * C_ + c0 + 1] = (t0.y + t1.y + t2.y + t3.y) * inv;
        out_pf[b * C_ + c0 + 2] = (t0.z + t1.z + t2.z + t3.z) * inv;
        out_pf[b * C_ + c0 + 3] = (t0.w + t1.w + t2.w + t3.w) * inv;
    }
}

// ---------------------------------------------------------------------------
// K2: fused 2-layer MLP (unchanged).
// ---------------------------------------------------------------------------
__global__ __launch_bounds__(256) void kern_mlp(
    const float* __restrict__ pf, const float* __restrict__ lang,
    const float* __restrict__ cg_w1, const float* __restrict__ cg_b1,
    const float* __restrict__ cg_w2, const float* __restrict__ cg_b2,
    const float* __restrict__ lf_w1, const float* __restrict__ lf_b1,
    const float* __restrict__ lf_w2, const float* __restrict__ lf_b2,
    float* __restrict__ ws_cg, float* __restrict__ out_gl)
{
    const int b = blockIdx.x >> 1;
    const int which = blockIdx.x & 1;
    const int t = threadIdx.x;
    __shared__ float fus[512];
    __shared__ float hid[256];

    fus[t]       = pf[b * 256 + t];
    fus[256 + t] = lang[b * 256 + t];

    const float* w1 = which ? lf_w1 : cg_w1;
    const float* b1 = which ? lf_b1 : cg_b1;
    const float* w2 = which ? lf_w2 : cg_w2;
    const float* b2 = which ? lf_b2 : cg_b2;
    __syncthreads();

    const f32x4* wv = (const f32x4*)(w1 + (size_t)t * 512);
    const f32x4* fv = (const f32x4*)fus;
    float s = 0.0f;
    #pragma unroll 4
    for (int k = 0; k < 128; ++k) {
        f32x4 f = fv[k], w = wv[k];
        s = fmaf(f.x, w.x, fmaf(f.y, w.y, fmaf(f.z, w.z, fmaf(f.w, w.w, s))));
    }
    hid[t] = fmaxf(s + b1[t], 0.0f);
    __syncthreads();

    const f32x4* w2v = (const f32x4*)(w2 + (size_t)t * 256);
    const f32x4* hv = (const f32x4*)hid;
    float s2 = 0.0f;
    #pragma unroll 4
    for (int k = 0; k < 64; ++k) {
        f32x4 h = hv[k], w = w2v[k];
        s2 = fmaf(h.x, w.x, fmaf(h.y, w.y, fmaf(h.z, w.z, fmaf(h.w, w.w, s2))));
    }
    s2 += b2[t];
    if (which == 0) {
        ws_cg[b * 256 + t] = 1.0f + 0.5f / (1.0f + expf(-s2));   // pre-biased gate
    } else {
        out_gl[b * 256 + t] = fus[256 + t] + 0.4f * tanhf(s2);
    }
}

// ---------------------------------------------------------------------------
// K3: guided. Header rebuilds rm into LDS (no rm global stream in hot loop).
// Hot loop: contiguous 64 KB read sweep -> contiguous nt-store sweep.
// ---------------------------------------------------------------------------
__global__ __launch_bounds__(256) void kern_guided(
    const float* __restrict__ feat, const float* __restrict__ xywh,
    const float* __restrict__ conv1_w, const float* __restrict__ conv1_b,
    const float* __restrict__ conv2_w, const float* __restrict__ conv2_b,
    const float* __restrict__ ws_cg, float* __restrict__ out_gf)
{
    const int blk = blockIdx.x;          // b*64 + g
    const int b = blk >> 6;
    const int c0 = (blk & 63) * RPB;
    const int t = threadIdx.x;

    __shared__ float sw1[16 * 9];
    __shared__ float sb1[16];
    __shared__ float sw2[16];
    __shared__ float tbl[64];
    __shared__ int   xpat[64];
    __shared__ int   ypat[64];
    __shared__ f32x4 rm4_lds[HW4];

    float* rm_lds = (float*)rm4_lds;

    if (t < 144)                 sw1[t]       = conv1_w[t];
    else if (t < 160)            sb1[t - 144] = conv1_b[t - 144];
    else if (t < 176)            sw2[t - 160] = conv2_w[t - 160];
    const float b2v = conv2_b[0];

    const BoxParams bp = box_math(xywh, b);
    __syncthreads();
    build_tables(t, bp, b2v, sw1, sb1, sw2, xpat, ypat, tbl);
    __syncthreads();
    // rebuild rm into LDS (precompute the 1+0.6*rm factor directly)
    for (int p = t; p < HW; p += 256) {
        const int y = p >> 6;
        const int x = p & 63;
        rm_lds[p] = 1.0f + 0.6f * tbl[ypat[y] * 8 + xpat[x]];
    }
    __syncthreads();

    const float g0 = ws_cg[b * C_ + c0 + 0];
    const float g1 = ws_cg[b * C_ + c0 + 1];
    const float g2 = ws_cg[b * C_ + c0 + 2];
    const float g3 = ws_cg[b * C_ + c0 + 3];

    const size_t row0 = ((size_t)b * C_ + c0) * HW;
    const f32x4* fs = (const f32x4*)(feat + row0);
    f32x4* os = (f32x4*)(out_gf + row0);

    #pragma unroll
    for (int r = 0; r < 4; ++r) {
        const float gr = (r == 0) ? g0 : (r == 1) ? g1 : (r == 2) ? g2 : g3;
        f32x4 f0 = fs[t + (r * 4 + 0) * 256];
        f32x4 f1 = fs[t + (r * 4 + 1) * 256];
        f32x4 f2 = fs[t + (r * 4 + 2) * 256];
        f32x4 f3 = fs[t + (r * 4 + 3) * 256];
        f32x4 m0 = rm4_lds[t];
        f32x4 m1 = rm4_lds[t + 256];
        f32x4 m2 = rm4_lds[t + 512];
        f32x4 m3 = rm4_lds[t + 768];
        f32x4 o;
        o.x = f0.x * m0.x * gr; o.y = f0.y * m0.y * gr;
        o.z = f0.z * m0.z * gr; o.w = f0.w * m0.w * gr;
        __builtin_nontemporal_store(o, &os[t + (r * 4 + 0) * 256]);
        o.x = f1.x * m1.x * gr; o.y = f1.y * m1.y * gr;
        o.z = f1.z * m1.z * gr; o.w = f1.w * m1.w * gr;
        __builtin_nontemporal_store(o, &os[t + (r * 4 + 1) * 256]);
        o.x = f2.x * m2.x * gr; o.y = f2.y * m2.y * gr;
        o.z = f2.z * m2.z * gr; o.w = f2.w * m2.w * gr;
        __builtin_nontemporal_store(o, &os[t + (r * 4 + 2) * 256]);
        o.x = f3.x * m3.x * gr; o.y = f3.y * m3.y * gr;
        o.z = f3.z * m3.z * gr; o.w = f3.w * m3.w * gr;
        __builtin_nontemporal_store(o, &os[t + (r * 4 + 3) * 256]);
    }
}

extern "C" void kernel_launch(void* const* d_in, const int* in_sizes, int n_in,
                              void* d_out, int out_size, void* d_ws, size_t ws_size,
                              hipStream_t stream) {
    const float* feat     = (const float*)d_in[0];
    const float* lang     = (const float*)d_in[1];
    const float* xywh     = (const float*)d_in[2];
    const float* conv1_w  = (const float*)d_in[3];
    const float* conv1_b  = (const float*)d_in[4];
    const float* conv2_w  = (const float*)d_in[5];
    const float* conv2_b  = (const float*)d_in[6];
    const float* cg_w1    = (const float*)d_in[7];
    const float* cg_b1    = (const float*)d_in[8];
    const float* cg_w2    = (const float*)d_in[9];
    const float* cg_b2    = (const float*)d_in[10];
    const float* lf_w1    = (const float*)d_in[11];
    const float* lf_b1    = (const float*)d_in[12];
    const float* lf_w2    = (const float*)d_in[13];
    const float* lf_b2    = (const float*)d_in[14];

    float* out = (float*)d_out;
    const size_t N_GF = (size_t)B_ * C_ * HW;    // 33554432
    float* out_gf    = out;
    float* out_gl    = out_gf + N_GF;            // 8192
    float* out_boxes = out_gl + (size_t)B_ * C_; // 128
    float* out_rm    = out_boxes + B_ * 4;       // 131072
    float* out_pf    = out_rm + (size_t)B_ * HW; // 8192

    float* wsf   = (float*)d_ws;
    float* ws_cg = wsf;                    // 8192 pre-biased gates

    (void)ws_size; (void)in_sizes; (void)n_in; (void)out_size;

    kern_pf<<<B_ * C_ / RPB, 256, 0, stream>>>(feat, xywh,
                                               conv1_w, conv1_b, conv2_w, conv2_b,
                                               out_boxes, out_rm, out_pf);
    kern_mlp<<<B_ * 2, 256, 0, stream>>>(out_pf, lang,
                                         cg_w1, cg_b1, cg_w2, cg_b2,
                                         lf_w1, lf_b1, lf_w2, lf_b2,
                                         ws_cg, out_gl);
    kern_guided<<<B_ * C_ / RPB, 256, 0, stream>>>(feat, xywh,
                                                   conv1_w, conv1_b, conv2_w, conv2_b,
                                                   ws_cg, out_gf);
}